// Round 1
// baseline (1559.977 us; speedup 1.0000x reference)
//
#include <hip/hip_runtime.h>
#include <cstdint>
#include <cstddef>

#define D_MODEL 768
#define D_STATE 16
#define D_CONV  4
#define INNER   1536
#define BATCH   2
#define SEQLEN  2048
#define M_TOK   (BATCH * SEQLEN)   // 4096

// ---------------------------------------------------------------------------
// Tiled fp32 GEMM, C[m,n] = sum_k A[m,k] * B[n,k]  (both row-major, K contig)
// MODE 0: plain store.  MODE 1: softplus(val + bias1[n] + bias2[n]).
// BM=BN=128, BK=8, 256 threads, 8x8 accumulators per thread.
// ---------------------------------------------------------------------------
template <int MODE>
__global__ __launch_bounds__(256) void gemm_nt(
    const float* __restrict__ A, const float* __restrict__ B,
    float* __restrict__ C,
    const float* __restrict__ bias1, const float* __restrict__ bias2,
    int M, int N, int K)
{
    constexpr int BM = 128, BN = 128, BK = 8;
    __shared__ float As[BK][BM + 4];
    __shared__ float Bs[BK][BN + 4];

    const int tid = threadIdx.x;
    const int bm = blockIdx.y * BM;
    const int bn = blockIdx.x * BN;
    const int tx = tid & 15;    // 0..15 -> n groups of 8
    const int ty = tid >> 4;    // 0..15 -> m groups of 8
    const int lrow = tid >> 1;        // 0..127
    const int lk   = (tid & 1) << 2;  // 0 or 4

    const float* Ap = A + (size_t)(bm + lrow) * K + lk;
    const float* Bp = B + (size_t)(bn + lrow) * K + lk;

    float acc[8][8] = {};

    for (int k0 = 0; k0 < K; k0 += BK) {
        const float4 av = *(const float4*)(Ap + k0);
        const float4 bv = *(const float4*)(Bp + k0);
        __syncthreads();   // previous tile fully consumed before overwrite
        As[lk + 0][lrow] = av.x; As[lk + 1][lrow] = av.y;
        As[lk + 2][lrow] = av.z; As[lk + 3][lrow] = av.w;
        Bs[lk + 0][lrow] = bv.x; Bs[lk + 1][lrow] = bv.y;
        Bs[lk + 2][lrow] = bv.z; Bs[lk + 3][lrow] = bv.w;
        __syncthreads();

#pragma unroll
        for (int k = 0; k < BK; ++k) {
            const float4 a0 = *(const float4*)&As[k][ty * 8];
            const float4 a1 = *(const float4*)&As[k][ty * 8 + 4];
            const float4 b0 = *(const float4*)&Bs[k][tx * 8];
            const float4 b1 = *(const float4*)&Bs[k][tx * 8 + 4];
            const float am[8] = {a0.x, a0.y, a0.z, a0.w, a1.x, a1.y, a1.z, a1.w};
            const float bb[8] = {b0.x, b0.y, b0.z, b0.w, b1.x, b1.y, b1.z, b1.w};
#pragma unroll
            for (int i = 0; i < 8; ++i)
#pragma unroll
                for (int j = 0; j < 8; ++j)
                    acc[i][j] = fmaf(am[i], bb[j], acc[i][j]);
        }
    }

#pragma unroll
    for (int i = 0; i < 8; ++i) {
        const int row = bm + ty * 8 + i;
        float vals[8];
#pragma unroll
        for (int j = 0; j < 8; ++j) {
            float v = acc[i][j];
            if constexpr (MODE == 1) {
                const int col = bn + tx * 8 + j;
                const float x = v + bias1[col] + bias2[col];
                v = (x > 20.f) ? x : log1pf(expf(x));
            }
            vals[j] = v;
        }
        float* crow = C + (size_t)row * N + bn + tx * 8;
        *(float4*)(crow + 0) = make_float4(vals[0], vals[1], vals[2], vals[3]);
        *(float4*)(crow + 4) = make_float4(vals[4], vals[5], vals[6], vals[7]);
    }
}

// ---------------------------------------------------------------------------
// Depthwise causal conv (width 4) + bias + SiLU.
// Reads proj half of xz [m, 0..1536), writes u [m, c] (row-major, c contig).
// One thread per (m, 4 channels).
// ---------------------------------------------------------------------------
__global__ __launch_bounds__(256) void conv_silu_kernel(
    const float* __restrict__ xz, const float* __restrict__ cw,
    const float* __restrict__ cb, float* __restrict__ u)
{
    const int idx = blockIdx.x * 256 + threadIdx.x;   // 0 .. 4096*384-1
    const int c4 = (idx % (INNER / 4)) * 4;
    const int m  = idx / (INNER / 4);
    if (m >= M_TOK) return;
    const int b = m >> 11;        // / SEQLEN
    const int l = m & (SEQLEN - 1);

    float wt[4][4];
#pragma unroll
    for (int i = 0; i < 4; ++i) {
        const float4 w = *(const float4*)&cw[(c4 + i) * 4];
        wt[i][0] = w.x; wt[i][1] = w.y; wt[i][2] = w.z; wt[i][3] = w.w;
    }
    const float4 bias = *(const float4*)&cb[c4];
    float a[4] = {bias.x, bias.y, bias.z, bias.w};

#pragma unroll
    for (int j = 0; j < 4; ++j) {
        const int ll = l - 3 + j;
        if (ll >= 0) {
            const float4 x = *(const float4*)&xz[(size_t)(b * SEQLEN + ll) * (2 * INNER) + c4];
            a[0] = fmaf(x.x, wt[0][j], a[0]);
            a[1] = fmaf(x.y, wt[1][j], a[1]);
            a[2] = fmaf(x.z, wt[2][j], a[2]);
            a[3] = fmaf(x.w, wt[3][j], a[3]);
        }
    }
    float4 o;
    o.x = a[0] / (1.f + __expf(-a[0]));
    o.y = a[1] / (1.f + __expf(-a[1]));
    o.z = a[2] / (1.f + __expf(-a[2]));
    o.w = a[3] / (1.f + __expf(-a[3]));
    *(float4*)&u[(size_t)m * INNER + c4] = o;
}

// ---------------------------------------------------------------------------
// Selective scan: 16 lanes per channel (lane = state n), sequential over L.
// h = exp(dt*A)*h + dt*u*B ; y = sum_n h*C ; yg = (y + D*u)*silu(z)
// Block = 256 threads = 16 channels. Grid = 3072/16 = 192 blocks.
// ---------------------------------------------------------------------------
__global__ __launch_bounds__(256) void scan_kernel(
    const float* __restrict__ dt, const float* __restrict__ u,
    const float* __restrict__ xz, const float* __restrict__ A_log,
    const float* __restrict__ Bp, const float* __restrict__ Cp,
    const float* __restrict__ Dp, float* __restrict__ yg)
{
    const int tid = threadIdx.x;
    const int n = tid & 15;
    const int ch = blockIdx.x * 16 + (tid >> 4);   // 0..3071
    const int b = ch / INNER;
    const int d = ch - b * INNER;

    const float A2 = -expf(A_log[d * D_STATE + n]) * 1.44269504f; // A*log2(e)
    const float Bn = Bp[d * D_STATE + n];
    const float Cn = Cp[d * D_STATE + n];
    const float Dd = Dp[d];

    const float* dtp = dt + (size_t)b * SEQLEN * INNER + d;
    const float* up  = u  + (size_t)b * SEQLEN * INNER + d;
    const float* zp  = xz + (size_t)b * SEQLEN * (2 * INNER) + INNER + d;
    float* ygp = yg + (size_t)b * SEQLEN * INNER + d;

    float h = 0.f;
    float dtv = dtp[0];
    float uv  = up[0];
    float zv  = zp[0];

    for (int l = 0; l < SEQLEN; ++l) {
        float dtn = 0.f, un = 0.f, zn = 0.f;
        if (l + 1 < SEQLEN) {     // prefetch next step (off the h-chain)
            dtn = dtp[(size_t)(l + 1) * INNER];
            un  = up[(size_t)(l + 1) * INNER];
            zn  = zp[(size_t)(l + 1) * (2 * INNER)];
        }
        const float dA  = exp2f(dtv * A2);
        const float dBu = dtv * uv * Bn;
        h = fmaf(dA, h, dBu);
        float p = h * Cn;
        p += __shfl_xor(p, 1, 16);
        p += __shfl_xor(p, 2, 16);
        p += __shfl_xor(p, 4, 16);
        p += __shfl_xor(p, 8, 16);
        if (n == 0) {
            const float sig = 1.f / (1.f + __expf(-zv));
            ygp[(size_t)l * INNER] = (p + Dd * uv) * (zv * sig);
        }
        dtv = dtn; uv = un; zv = zn;
    }
}

// ---------------------------------------------------------------------------
extern "C" void kernel_launch(void* const* d_in, const int* in_sizes, int n_in,
                              void* d_out, int out_size, void* d_ws, size_t ws_size,
                              hipStream_t stream)
{
    const float* hs      = (const float*)d_in[0];   // (B, L, 768)
    const float* in_w    = (const float*)d_in[1];   // (3072, 768)
    const float* out_w   = (const float*)d_in[2];   // (768, 1536)
    const float* dt_w    = (const float*)d_in[3];   // (1536, 1536)
    const float* dt_b    = (const float*)d_in[4];   // (1536,)
    const float* conv_w  = (const float*)d_in[5];   // (1536, 4)
    const float* conv_b  = (const float*)d_in[6];   // (1536,)
    const float* A_log   = (const float*)d_in[7];   // (1536, 16)
    const float* Bp      = (const float*)d_in[8];   // (1536, 16)
    const float* Cp      = (const float*)d_in[9];   // (1536, 16)
    const float* Dp      = (const float*)d_in[10];  // (1536,)
    const float* dt_bias = (const float*)d_in[11];  // (1536,)
    float* out = (float*)d_out;

    float* xz = (float*)d_ws;                                 // [4096, 3072]
    float* u  = xz + (size_t)M_TOK * 2 * INNER;               // [4096, 1536]
    float* dt = u  + (size_t)M_TOK * INNER;                   // [4096, 1536]
    float* yg = dt + (size_t)M_TOK * INNER;                   // [4096, 1536]

    const dim3 blk(256);

    // 1) in_proj: xz[m, 0..3072) = hs @ in_w^T
    gemm_nt<0><<<dim3((2 * INNER) / 128, M_TOK / 128), blk, 0, stream>>>(
        hs, in_w, xz, nullptr, nullptr, M_TOK, 2 * INNER, D_MODEL);

    // 2) causal depthwise conv + SiLU -> u[m, c]
    conv_silu_kernel<<<dim3((M_TOK * (INNER / 4)) / 256), blk, 0, stream>>>(
        xz, conv_w, conv_b, u);

    // 3) dt = softplus(u @ dt_w^T + dt_proj_b + dt_bias)
    gemm_nt<1><<<dim3(INNER / 128, M_TOK / 128), blk, 0, stream>>>(
        u, dt_w, dt, dt_b, dt_bias, M_TOK, INNER, INNER);

    // 4) selective scan + gating -> yg[m, d]
    scan_kernel<<<dim3((BATCH * INNER) / 16), blk, 0, stream>>>(
        dt, u, xz, A_log, Bp, Cp, Dp, yg);

    // 5) out_proj: out = yg @ out_w^T
    gemm_nt<0><<<dim3(D_MODEL / 128, M_TOK / 128), blk, 0, stream>>>(
        yg, out_w, out, nullptr, nullptr, M_TOK, D_MODEL, INNER);
}

// Round 2
// 996.906 us; speedup vs baseline: 1.5648x; 1.5648x over previous
//
#include <hip/hip_runtime.h>
#include <cstdint>
#include <cstddef>

#define D_MODEL 768
#define D_STATE 16
#define D_CONV  4
#define INNER   1536
#define BATCH   2
#define SEQLEN  2048
#define M_TOK   (BATCH * SEQLEN)   // 4096
#define NCH     (BATCH * INNER)    // 3072 channels
#define NCHUNK  16
#define CL      (SEQLEN / NCHUNK)  // 128 steps per chunk

// ---------------------------------------------------------------------------
// Tiled fp32 GEMM, C[m,n] = sum_k A[m,k] * B[n,k]  (both row-major, K contig)
// MODE 0: plain store.  MODE 1: softplus(val + bias1[n] + bias2[n]).
// ---------------------------------------------------------------------------
template <int MODE>
__global__ __launch_bounds__(256) void gemm_nt(
    const float* __restrict__ A, const float* __restrict__ B,
    float* __restrict__ C,
    const float* __restrict__ bias1, const float* __restrict__ bias2,
    int M, int N, int K)
{
    constexpr int BM = 128, BN = 128, BK = 8;
    __shared__ float As[BK][BM + 4];
    __shared__ float Bs[BK][BN + 4];

    const int tid = threadIdx.x;
    const int bm = blockIdx.y * BM;
    const int bn = blockIdx.x * BN;
    const int tx = tid & 15;
    const int ty = tid >> 4;
    const int lrow = tid >> 1;
    const int lk   = (tid & 1) << 2;

    const float* Ap = A + (size_t)(bm + lrow) * K + lk;
    const float* Bp = B + (size_t)(bn + lrow) * K + lk;

    float acc[8][8] = {};

    for (int k0 = 0; k0 < K; k0 += BK) {
        const float4 av = *(const float4*)(Ap + k0);
        const float4 bv = *(const float4*)(Bp + k0);
        __syncthreads();
        As[lk + 0][lrow] = av.x; As[lk + 1][lrow] = av.y;
        As[lk + 2][lrow] = av.z; As[lk + 3][lrow] = av.w;
        Bs[lk + 0][lrow] = bv.x; Bs[lk + 1][lrow] = bv.y;
        Bs[lk + 2][lrow] = bv.z; Bs[lk + 3][lrow] = bv.w;
        __syncthreads();

#pragma unroll
        for (int k = 0; k < BK; ++k) {
            const float4 a0 = *(const float4*)&As[k][ty * 8];
            const float4 a1 = *(const float4*)&As[k][ty * 8 + 4];
            const float4 b0 = *(const float4*)&Bs[k][tx * 8];
            const float4 b1 = *(const float4*)&Bs[k][tx * 8 + 4];
            const float am[8] = {a0.x, a0.y, a0.z, a0.w, a1.x, a1.y, a1.z, a1.w};
            const float bb[8] = {b0.x, b0.y, b0.z, b0.w, b1.x, b1.y, b1.z, b1.w};
#pragma unroll
            for (int i = 0; i < 8; ++i)
#pragma unroll
                for (int j = 0; j < 8; ++j)
                    acc[i][j] = fmaf(am[i], bb[j], acc[i][j]);
        }
    }

#pragma unroll
    for (int i = 0; i < 8; ++i) {
        const int row = bm + ty * 8 + i;
        float vals[8];
#pragma unroll
        for (int j = 0; j < 8; ++j) {
            float v = acc[i][j];
            if constexpr (MODE == 1) {
                const int col = bn + tx * 8 + j;
                const float x = v + bias1[col] + bias2[col];
                v = (x > 20.f) ? x : log1pf(expf(x));
            }
            vals[j] = v;
        }
        float* crow = C + (size_t)row * N + bn + tx * 8;
        *(float4*)(crow + 0) = make_float4(vals[0], vals[1], vals[2], vals[3]);
        *(float4*)(crow + 4) = make_float4(vals[4], vals[5], vals[6], vals[7]);
    }
}

// ---------------------------------------------------------------------------
// Depthwise causal conv (width 4) + bias + SiLU -> u[m, c]
// ---------------------------------------------------------------------------
__global__ __launch_bounds__(256) void conv_silu_kernel(
    const float* __restrict__ xz, const float* __restrict__ cw,
    const float* __restrict__ cb, float* __restrict__ u)
{
    const int idx = blockIdx.x * 256 + threadIdx.x;
    const int c4 = (idx % (INNER / 4)) * 4;
    const int m  = idx / (INNER / 4);
    if (m >= M_TOK) return;
    const int b = m >> 11;
    const int l = m & (SEQLEN - 1);

    float wt[4][4];
#pragma unroll
    for (int i = 0; i < 4; ++i) {
        const float4 w = *(const float4*)&cw[(c4 + i) * 4];
        wt[i][0] = w.x; wt[i][1] = w.y; wt[i][2] = w.z; wt[i][3] = w.w;
    }
    const float4 bias = *(const float4*)&cb[c4];
    float a[4] = {bias.x, bias.y, bias.z, bias.w};

#pragma unroll
    for (int j = 0; j < 4; ++j) {
        const int ll = l - 3 + j;
        if (ll >= 0) {
            const float4 x = *(const float4*)&xz[(size_t)(b * SEQLEN + ll) * (2 * INNER) + c4];
            a[0] = fmaf(x.x, wt[0][j], a[0]);
            a[1] = fmaf(x.y, wt[1][j], a[1]);
            a[2] = fmaf(x.z, wt[2][j], a[2]);
            a[3] = fmaf(x.w, wt[3][j], a[3]);
        }
    }
    float4 o;
    o.x = a[0] / (1.f + __expf(-a[0]));
    o.y = a[1] / (1.f + __expf(-a[1]));
    o.z = a[2] / (1.f + __expf(-a[2]));
    o.w = a[3] / (1.f + __expf(-a[3]));
    *(float4*)&u[(size_t)m * INNER + c4] = o;
}

// ---------------------------------------------------------------------------
// Chunked scan, pass 1: per (chunk, channel) local scan with h0=0.
// Records end-state h and decay product P = prod(dA) per (chunk, ch, n).
// Block = 256 = 16 channels x 16 states. Grid = (192, NCHUNK).
// ---------------------------------------------------------------------------
__global__ __launch_bounds__(256) void scan_pass1(
    const float* __restrict__ dt, const float* __restrict__ u,
    const float* __restrict__ A_log, const float* __restrict__ Bp,
    float* __restrict__ hend, float* __restrict__ Pprod)
{
    const int tid = threadIdx.x;
    const int n = tid & 15;
    const int ch = blockIdx.x * 16 + (tid >> 4);
    const int c = blockIdx.y;
    const int b = ch / INNER;
    const int d = ch - b * INNER;

    const float A2 = -expf(A_log[d * D_STATE + n]) * 1.44269504f;
    const float Bn = Bp[d * D_STATE + n];

    const float* dtp = dt + (size_t)(b * SEQLEN + c * CL) * INNER + d;
    const float* up  = u  + (size_t)(b * SEQLEN + c * CL) * INNER + d;

    float h = 0.f, P = 1.f;
    // lane n pre-loads step (g*16 + n); values broadcast per-step via shfl
    float dt16 = dtp[(size_t)n * INNER];
    float u16  = up[(size_t)n * INNER];

    for (int g = 0; g < CL / 16; ++g) {
        float dtn = 0.f, un = 0.f;
        if (g + 1 < CL / 16) {
            dtn = dtp[(size_t)((g + 1) * 16 + n) * INNER];
            un  = up[(size_t)((g + 1) * 16 + n) * INNER];
        }
#pragma unroll
        for (int s = 0; s < 16; ++s) {
            const float dtv = __shfl(dt16, s, 16);
            const float uv  = __shfl(u16, s, 16);
            const float dA = exp2f(dtv * A2);
            h = fmaf(dA, h, dtv * uv * Bn);
            P *= dA;
        }
        dt16 = dtn; u16 = un;
    }
    const int idx = (c * NCH + ch) * D_STATE + n;
    hend[idx] = h;
    Pprod[idx] = P;
}

// ---------------------------------------------------------------------------
// Combine: sequential over the 16 chunks per (ch, n); emits each chunk's h0.
// ---------------------------------------------------------------------------
__global__ __launch_bounds__(256) void scan_combine(
    const float* __restrict__ hend, const float* __restrict__ Pprod,
    float* __restrict__ h0all)
{
    const int idx = blockIdx.x * 256 + threadIdx.x;   // < NCH*D_STATE
    float h0 = 0.f;
#pragma unroll
    for (int c = 0; c < NCHUNK; ++c) {
        const int o = c * (NCH * D_STATE) + idx;
        h0all[o] = h0;
        h0 = fmaf(Pprod[o], h0, hend[o]);
    }
}

// ---------------------------------------------------------------------------
// Pass 2: full scan per chunk from correct h0; y + D*u, gate with silu(z).
// Writes gated output IN PLACE over dt (safe: store value data-depends on
// the prior load of the same element).
// ---------------------------------------------------------------------------
__global__ __launch_bounds__(256) void scan_pass2(
    float* __restrict__ dt, const float* __restrict__ u,
    const float* __restrict__ xz, const float* __restrict__ A_log,
    const float* __restrict__ Bp, const float* __restrict__ Cp,
    const float* __restrict__ Dp, const float* __restrict__ h0all)
{
    const int tid = threadIdx.x;
    const int n = tid & 15;
    const int ch = blockIdx.x * 16 + (tid >> 4);
    const int c = blockIdx.y;
    const int b = ch / INNER;
    const int d = ch - b * INNER;

    const float A2 = -expf(A_log[d * D_STATE + n]) * 1.44269504f;
    const float Bn = Bp[d * D_STATE + n];
    const float Cn = Cp[d * D_STATE + n];
    const float Dd = Dp[d];

    float* dtp = dt + (size_t)(b * SEQLEN + c * CL) * INNER + d;
    const float* up = u + (size_t)(b * SEQLEN + c * CL) * INNER + d;
    const float* zp = xz + (size_t)(b * SEQLEN + c * CL) * (2 * INNER) + INNER + d;

    float h = h0all[c * (NCH * D_STATE) + ch * D_STATE + n];

    float dt16 = dtp[(size_t)n * INNER];
    float u16  = up[(size_t)n * INNER];
    float z16  = zp[(size_t)n * (2 * INNER)];

    for (int g = 0; g < CL / 16; ++g) {
        float dtn = 0.f, un = 0.f, zn = 0.f;
        if (g + 1 < CL / 16) {
            dtn = dtp[(size_t)((g + 1) * 16 + n) * INNER];
            un  = up[(size_t)((g + 1) * 16 + n) * INNER];
            zn  = zp[(size_t)((g + 1) * 16 + n) * (2 * INNER)];
        }
#pragma unroll
        for (int s = 0; s < 16; ++s) {
            const float dtv = __shfl(dt16, s, 16);
            const float uv  = __shfl(u16, s, 16);
            const float dA = exp2f(dtv * A2);
            h = fmaf(dA, h, dtv * uv * Bn);
            float p = h * Cn;
            p += __shfl_xor(p, 1, 16);
            p += __shfl_xor(p, 2, 16);
            p += __shfl_xor(p, 4, 16);
            p += __shfl_xor(p, 8, 16);
            if (n == s) {   // lane s owns step g*16+s: its own u16/z16 match
                const float sig = 1.f / (1.f + __expf(-z16));
                dtp[(size_t)(g * 16 + s) * INNER] = (p + Dd * u16) * (z16 * sig);
            }
        }
        dt16 = dtn; u16 = un; z16 = zn;
    }
}

// ---------------------------------------------------------------------------
extern "C" void kernel_launch(void* const* d_in, const int* in_sizes, int n_in,
                              void* d_out, int out_size, void* d_ws, size_t ws_size,
                              hipStream_t stream)
{
    const float* hs      = (const float*)d_in[0];
    const float* in_w    = (const float*)d_in[1];
    const float* out_w   = (const float*)d_in[2];
    const float* dt_w    = (const float*)d_in[3];
    const float* dt_b    = (const float*)d_in[4];
    const float* conv_w  = (const float*)d_in[5];
    const float* conv_b  = (const float*)d_in[6];
    const float* A_log   = (const float*)d_in[7];
    const float* Bp      = (const float*)d_in[8];
    const float* Cp      = (const float*)d_in[9];
    const float* Dp      = (const float*)d_in[10];
    const float* dt_bias = (const float*)d_in[11];
    float* out = (float*)d_out;

    float* xz    = (float*)d_ws;                               // [4096, 3072]
    float* u     = xz + (size_t)M_TOK * 2 * INNER;             // [4096, 1536]
    float* dt    = u  + (size_t)M_TOK * INNER;                 // [4096, 1536] -> becomes yg
    float* hend  = dt + (size_t)M_TOK * INNER;                 // [16, 3072, 16]
    float* Pprod = hend + (size_t)NCHUNK * NCH * D_STATE;
    float* h0all = Pprod + (size_t)NCHUNK * NCH * D_STATE;

    const dim3 blk(256);

    // 1) in_proj
    gemm_nt<0><<<dim3((2 * INNER) / 128, M_TOK / 128), blk, 0, stream>>>(
        hs, in_w, xz, nullptr, nullptr, M_TOK, 2 * INNER, D_MODEL);

    // 2) conv + SiLU
    conv_silu_kernel<<<dim3((M_TOK * (INNER / 4)) / 256), blk, 0, stream>>>(
        xz, conv_w, conv_b, u);

    // 3) dt = softplus(u @ dt_w^T + biases)
    gemm_nt<1><<<dim3(INNER / 128, M_TOK / 128), blk, 0, stream>>>(
        u, dt_w, dt, dt_b, dt_bias, M_TOK, INNER, INNER);

    // 4) chunked selective scan (3 kernels), gated output written over dt
    scan_pass1<<<dim3(NCH / 16, NCHUNK), blk, 0, stream>>>(
        dt, u, A_log, Bp, hend, Pprod);
    scan_combine<<<dim3((NCH * D_STATE) / 256), blk, 0, stream>>>(
        hend, Pprod, h0all);
    scan_pass2<<<dim3(NCH / 16, NCHUNK), blk, 0, stream>>>(
        dt, u, xz, A_log, Bp, Cp, Dp, h0all);

    // 5) out_proj: out = yg @ out_w^T   (yg aliases dt)
    gemm_nt<0><<<dim3(D_MODEL / 128, M_TOK / 128), blk, 0, stream>>>(
        dt, out_w, out, nullptr, nullptr, M_TOK, D_MODEL, INNER);
}

// Round 3
// 422.765 us; speedup vs baseline: 3.6899x; 2.3581x over previous
//
#include <hip/hip_runtime.h>
#include <cstdint>
#include <cstddef>

#define D_MODEL 768
#define D_STATE 16
#define D_CONV  4
#define INNER   1536
#define BATCH   2
#define SEQLEN  2048
#define M_TOK   (BATCH * SEQLEN)   // 4096
#define NCH     (BATCH * INNER)    // 3072
#define NCHUNK  16
#define CL      (SEQLEN / NCHUNK)  // 128

typedef unsigned short u16;
typedef __attribute__((ext_vector_type(4))) unsigned short us4;
typedef __attribute__((ext_vector_type(8))) short bf8;
typedef __attribute__((ext_vector_type(4))) float f32x4;

__device__ __forceinline__ u16 f2bf(float f) {
    uint32_t x = __float_as_uint(f);
    return (u16)((x + 0x7fffu + ((x >> 16) & 1u)) >> 16);
}
__device__ __forceinline__ float bf2f(u16 h) {
    return __uint_as_float(((uint32_t)h) << 16);
}

// ---------------------------------------------------------------------------
// fp32 -> (hi, lo) bf16 split, vectorized x4
// ---------------------------------------------------------------------------
__global__ __launch_bounds__(256) void cvt_hilo(
    const float* __restrict__ x, u16* __restrict__ hi, u16* __restrict__ lo, int n4)
{
    const int i = blockIdx.x * 256 + threadIdx.x;
    if (i >= n4) return;
    const float4 v = ((const float4*)x)[i];
    us4 h, l;
    h.x = f2bf(v.x); l.x = f2bf(v.x - bf2f(h.x));
    h.y = f2bf(v.y); l.y = f2bf(v.y - bf2f(h.y));
    h.z = f2bf(v.z); l.z = f2bf(v.z - bf2f(h.z));
    h.w = f2bf(v.w); l.w = f2bf(v.w - bf2f(h.w));
    ((us4*)hi)[i] = h;
    ((us4*)lo)[i] = l;
}

// ---------------------------------------------------------------------------
// Split-bf16 MFMA GEMM: C[m,n] = sum_k A[m,k]*B[n,k], A,B given as hi/lo bf16.
// 128x128 tile, BK=32, 256 thr = 4 waves (64x64 out each, 4x4 16x16 frags).
// acc += Ah*Bh + Ah*Bl + Al*Bh   (3 MFMA per fragment pair)
// MODE 0: plain store. MODE 1: softplus(v + bias1[n] + bias2[n]).
// ---------------------------------------------------------------------------
template <int MODE>
__global__ __launch_bounds__(256) void gemm_mfma(
    const u16* __restrict__ Ah_g, const u16* __restrict__ Al_g,
    const u16* __restrict__ Bh_g, const u16* __restrict__ Bl_g,
    float* __restrict__ C, const float* __restrict__ bias1,
    const float* __restrict__ bias2, int M, int N, int K)
{
    __shared__ u16 sAh[128 * 32], sAl[128 * 32], sBh[128 * 32], sBl[128 * 32];
    const int tid = threadIdx.x;
    const int w = tid >> 6;
    const int lane = tid & 63;
    const int bm = blockIdx.y * 128;
    const int bn = blockIdx.x * 128;
    const int wm = (w >> 1) * 64;
    const int wn = (w & 1) * 64;

    // staging: tile row = p*64 + w*16 + (lane>>2), k-col = (lane&3)*8
    const int st_row = w * 16 + (lane >> 2);
    const int st_col = (lane & 3) * 8;
    const u16* a_h = Ah_g + (size_t)(bm + st_row) * K + st_col;
    const u16* a_l = Al_g + (size_t)(bm + st_row) * K + st_col;
    const u16* b_h = Bh_g + (size_t)(bn + st_row) * K + st_col;
    const u16* b_l = Bl_g + (size_t)(bn + st_row) * K + st_col;
    const size_t rowskip = (size_t)64 * K;

    f32x4 acc[4][4] = {};

    const int fr = lane & 15;
    const int fk = (lane >> 4) * 8;

    for (int k0 = 0; k0 < K; k0 += 32) {
        __syncthreads();
#define STAGE(gp, lds)                                                              \
        __builtin_amdgcn_global_load_lds(                                           \
            (const __attribute__((address_space(1))) void*)(gp + k0),               \
            (__attribute__((address_space(3))) void*)((char*)(lds) + w * 1024),     \
            16, 0, 0);                                                              \
        __builtin_amdgcn_global_load_lds(                                           \
            (const __attribute__((address_space(1))) void*)(gp + k0 + rowskip),     \
            (__attribute__((address_space(3))) void*)((char*)(lds) + 4096 + w * 1024), \
            16, 0, 0);
        STAGE(a_h, sAh) STAGE(a_l, sAl) STAGE(b_h, sBh) STAGE(b_l, sBl)
#undef STAGE
        asm volatile("s_waitcnt vmcnt(0)" ::: "memory");
        __syncthreads();

        bf8 ah[4], al[4], bh[4], bl[4];
#pragma unroll
        for (int i = 0; i < 4; ++i) {
            ah[i] = *(const bf8*)&sAh[(wm + i * 16 + fr) * 32 + fk];
            al[i] = *(const bf8*)&sAl[(wm + i * 16 + fr) * 32 + fk];
            bh[i] = *(const bf8*)&sBh[(wn + i * 16 + fr) * 32 + fk];
            bl[i] = *(const bf8*)&sBl[(wn + i * 16 + fr) * 32 + fk];
        }
#pragma unroll
        for (int i = 0; i < 4; ++i)
#pragma unroll
            for (int j = 0; j < 4; ++j) {
                acc[i][j] = __builtin_amdgcn_mfma_f32_16x16x32_bf16(ah[i], bh[j], acc[i][j], 0, 0, 0);
                acc[i][j] = __builtin_amdgcn_mfma_f32_16x16x32_bf16(ah[i], bl[j], acc[i][j], 0, 0, 0);
                acc[i][j] = __builtin_amdgcn_mfma_f32_16x16x32_bf16(al[i], bh[j], acc[i][j], 0, 0, 0);
            }
    }

    const int r0 = (lane >> 4) * 4;
#pragma unroll
    for (int i = 0; i < 4; ++i) {
        const int row0 = bm + wm + i * 16 + r0;
#pragma unroll
        for (int j = 0; j < 4; ++j) {
            const int col = bn + wn + j * 16 + fr;
            float add = 0.f;
            if constexpr (MODE == 1) add = bias1[col] + bias2[col];
#pragma unroll
            for (int r = 0; r < 4; ++r) {
                float v = acc[i][j][r];
                if constexpr (MODE == 1) {
                    const float xx = v + add;
                    v = (xx > 20.f) ? xx : log1pf(expf(xx));
                }
                C[(size_t)(row0 + r) * N + col] = v;
            }
        }
    }
}

// ---------------------------------------------------------------------------
// Depthwise causal conv (width 4) + bias + SiLU -> u fp32 AND u hi/lo bf16
// ---------------------------------------------------------------------------
__global__ __launch_bounds__(256) void conv_silu_kernel(
    const float* __restrict__ xz, const float* __restrict__ cw,
    const float* __restrict__ cb, float* __restrict__ u,
    u16* __restrict__ uh, u16* __restrict__ ul)
{
    const int idx = blockIdx.x * 256 + threadIdx.x;
    const int c4 = (idx % (INNER / 4)) * 4;
    const int m  = idx / (INNER / 4);
    if (m >= M_TOK) return;
    const int b = m >> 11;
    const int l = m & (SEQLEN - 1);

    float wt[4][4];
#pragma unroll
    for (int i = 0; i < 4; ++i) {
        const float4 wv = *(const float4*)&cw[(c4 + i) * 4];
        wt[i][0] = wv.x; wt[i][1] = wv.y; wt[i][2] = wv.z; wt[i][3] = wv.w;
    }
    const float4 bias = *(const float4*)&cb[c4];
    float a[4] = {bias.x, bias.y, bias.z, bias.w};

#pragma unroll
    for (int j = 0; j < 4; ++j) {
        const int ll = l - 3 + j;
        if (ll >= 0) {
            const float4 x = *(const float4*)&xz[(size_t)(b * SEQLEN + ll) * (2 * INNER) + c4];
            a[0] = fmaf(x.x, wt[0][j], a[0]);
            a[1] = fmaf(x.y, wt[1][j], a[1]);
            a[2] = fmaf(x.z, wt[2][j], a[2]);
            a[3] = fmaf(x.w, wt[3][j], a[3]);
        }
    }
    float4 o;
    o.x = a[0] / (1.f + __expf(-a[0]));
    o.y = a[1] / (1.f + __expf(-a[1]));
    o.z = a[2] / (1.f + __expf(-a[2]));
    o.w = a[3] / (1.f + __expf(-a[3]));
    *(float4*)&u[(size_t)m * INNER + c4] = o;

    us4 h, lo;
    h.x = f2bf(o.x); lo.x = f2bf(o.x - bf2f(h.x));
    h.y = f2bf(o.y); lo.y = f2bf(o.y - bf2f(h.y));
    h.z = f2bf(o.z); lo.z = f2bf(o.z - bf2f(h.z));
    h.w = f2bf(o.w); lo.w = f2bf(o.w - bf2f(h.w));
    const size_t vi = ((size_t)m * INNER + c4) / 4;
    ((us4*)uh)[vi] = h;
    ((us4*)ul)[vi] = lo;
}

// ---------------------------------------------------------------------------
// Chunked scan, pass 1: per (chunk, channel) local scan with h0=0.
// ---------------------------------------------------------------------------
__global__ __launch_bounds__(256) void scan_pass1(
    const float* __restrict__ dt, const float* __restrict__ u,
    const float* __restrict__ A_log, const float* __restrict__ Bp,
    float* __restrict__ hend, float* __restrict__ Pprod)
{
    const int tid = threadIdx.x;
    const int n = tid & 15;
    const int ch = blockIdx.x * 16 + (tid >> 4);
    const int c = blockIdx.y;
    const int b = ch / INNER;
    const int d = ch - b * INNER;

    const float A2 = -expf(A_log[d * D_STATE + n]) * 1.44269504f;
    const float Bn = Bp[d * D_STATE + n];

    const float* dtp = dt + (size_t)(b * SEQLEN + c * CL) * INNER + d;
    const float* up  = u  + (size_t)(b * SEQLEN + c * CL) * INNER + d;

    float h = 0.f, P = 1.f;
    float ld_dt = dtp[(size_t)n * INNER];
    float ld_u  = up[(size_t)n * INNER];

    for (int g = 0; g < CL / 16; ++g) {
        float nx_dt = 0.f, nx_u = 0.f;
        if (g + 1 < CL / 16) {
            nx_dt = dtp[(size_t)((g + 1) * 16 + n) * INNER];
            nx_u  = up[(size_t)((g + 1) * 16 + n) * INNER];
        }
#pragma unroll
        for (int s = 0; s < 16; ++s) {
            const float dtv = __shfl(ld_dt, s, 16);
            const float uv  = __shfl(ld_u, s, 16);
            const float dA = exp2f(dtv * A2);
            h = fmaf(dA, h, dtv * uv * Bn);
            P *= dA;
        }
        ld_dt = nx_dt; ld_u = nx_u;
    }
    const int o = (c * NCH + ch) * D_STATE + n;
    hend[o] = h;
    Pprod[o] = P;
}

// ---------------------------------------------------------------------------
// Combine: sequential over chunks per (ch, n); emits each chunk's h0.
// ---------------------------------------------------------------------------
__global__ __launch_bounds__(256) void scan_combine(
    const float* __restrict__ hend, const float* __restrict__ Pprod,
    float* __restrict__ h0all)
{
    const int idx = blockIdx.x * 256 + threadIdx.x;
    float h0 = 0.f;
#pragma unroll
    for (int c = 0; c < NCHUNK; ++c) {
        const int o = c * (NCH * D_STATE) + idx;
        h0all[o] = h0;
        h0 = fmaf(Pprod[o], h0, hend[o]);
    }
}

// ---------------------------------------------------------------------------
// Pass 2: scan per chunk from h0; y = (h.C + D*u)*silu(z) -> yg hi/lo bf16
// ---------------------------------------------------------------------------
__global__ __launch_bounds__(256) void scan_pass2(
    const float* __restrict__ dt, const float* __restrict__ u,
    const float* __restrict__ xz, const float* __restrict__ A_log,
    const float* __restrict__ Bp, const float* __restrict__ Cp,
    const float* __restrict__ Dp, const float* __restrict__ h0all,
    u16* __restrict__ ygh, u16* __restrict__ ygl)
{
    const int tid = threadIdx.x;
    const int n = tid & 15;
    const int ch = blockIdx.x * 16 + (tid >> 4);
    const int c = blockIdx.y;
    const int b = ch / INNER;
    const int d = ch - b * INNER;

    const float A2 = -expf(A_log[d * D_STATE + n]) * 1.44269504f;
    const float Bn = Bp[d * D_STATE + n];
    const float Cn = Cp[d * D_STATE + n];
    const float Dd = Dp[d];

    const float* dtp = dt + (size_t)(b * SEQLEN + c * CL) * INNER + d;
    const float* up  = u  + (size_t)(b * SEQLEN + c * CL) * INNER + d;
    const float* zp  = xz + (size_t)(b * SEQLEN + c * CL) * (2 * INNER) + INNER + d;
    u16* yhp = ygh + (size_t)(b * SEQLEN + c * CL) * INNER + d;
    u16* ylp = ygl + (size_t)(b * SEQLEN + c * CL) * INNER + d;

    float h = h0all[c * (NCH * D_STATE) + ch * D_STATE + n];

    float ld_dt = dtp[(size_t)n * INNER];
    float ld_u  = up[(size_t)n * INNER];
    float ld_z  = zp[(size_t)n * (2 * INNER)];

    for (int g = 0; g < CL / 16; ++g) {
        float nx_dt = 0.f, nx_u = 0.f, nx_z = 0.f;
        if (g + 1 < CL / 16) {
            nx_dt = dtp[(size_t)((g + 1) * 16 + n) * INNER];
            nx_u  = up[(size_t)((g + 1) * 16 + n) * INNER];
            nx_z  = zp[(size_t)((g + 1) * 16 + n) * (2 * INNER)];
        }
#pragma unroll
        for (int s = 0; s < 16; ++s) {
            const float dtv = __shfl(ld_dt, s, 16);
            const float uv  = __shfl(ld_u, s, 16);
            const float dA = exp2f(dtv * A2);
            h = fmaf(dA, h, dtv * uv * Bn);
            float p = h * Cn;
            p += __shfl_xor(p, 1, 16);
            p += __shfl_xor(p, 2, 16);
            p += __shfl_xor(p, 4, 16);
            p += __shfl_xor(p, 8, 16);
            if (n == s) {   // lane s owns step g*16+s
                const float sig = 1.f / (1.f + __expf(-ld_z));
                const float val = (p + Dd * ld_u) * (ld_z * sig);
                const u16 hv = f2bf(val);
                yhp[(size_t)(g * 16 + s) * INNER] = hv;
                ylp[(size_t)(g * 16 + s) * INNER] = f2bf(val - bf2f(hv));
            }
        }
        ld_dt = nx_dt; ld_u = nx_u; ld_z = nx_z;
    }
}

// ---------------------------------------------------------------------------
extern "C" void kernel_launch(void* const* d_in, const int* in_sizes, int n_in,
                              void* d_out, int out_size, void* d_ws, size_t ws_size,
                              hipStream_t stream)
{
    const float* hs      = (const float*)d_in[0];
    const float* in_w    = (const float*)d_in[1];
    const float* out_w   = (const float*)d_in[2];
    const float* dt_w    = (const float*)d_in[3];
    const float* dt_b    = (const float*)d_in[4];
    const float* conv_w  = (const float*)d_in[5];
    const float* conv_b  = (const float*)d_in[6];
    const float* A_log   = (const float*)d_in[7];
    const float* Bp      = (const float*)d_in[8];
    const float* Cp      = (const float*)d_in[9];
    const float* Dp      = (const float*)d_in[10];
    const float* dt_bias = (const float*)d_in[11];
    float* out = (float*)d_out;

    float* xz    = (float*)d_ws;                               // [4096, 3072] f32
    float* u     = xz + (size_t)M_TOK * 2 * INNER;             // [4096, 1536] f32
    float* dt    = u  + (size_t)M_TOK * INNER;                 // [4096, 1536] f32
    float* hend  = dt + (size_t)M_TOK * INNER;
    float* Pprod = hend + (size_t)NCHUNK * NCH * D_STATE;
    float* h0all = Pprod + (size_t)NCHUNK * NCH * D_STATE;
    u16* uh  = (u16*)(h0all + (size_t)NCHUNK * NCH * D_STATE);
    u16* ul  = uh  + (size_t)M_TOK * INNER;
    u16* hsh = ul  + (size_t)M_TOK * INNER;
    u16* hsl = hsh + (size_t)M_TOK * D_MODEL;
    u16* ygh = hsl + (size_t)M_TOK * D_MODEL;
    u16* ygl = ygh + (size_t)M_TOK * INNER;
    u16* iwh = ygl + (size_t)M_TOK * INNER;
    u16* iwl = iwh + (size_t)2 * INNER * D_MODEL;
    u16* dwh = iwl + (size_t)2 * INNER * D_MODEL;
    u16* dwl = dwh + (size_t)INNER * INNER;
    u16* owh = dwl + (size_t)INNER * INNER;
    u16* owl = owh + (size_t)D_MODEL * INNER;

    const dim3 blk(256);

    // hi/lo conversions (hs + weights)
    cvt_hilo<<<dim3(M_TOK * D_MODEL / 4 / 256), blk, 0, stream>>>(hs, hsh, hsl, M_TOK * D_MODEL / 4);
    cvt_hilo<<<dim3(2 * INNER * D_MODEL / 4 / 256), blk, 0, stream>>>(in_w, iwh, iwl, 2 * INNER * D_MODEL / 4);
    cvt_hilo<<<dim3(INNER * INNER / 4 / 256), blk, 0, stream>>>(dt_w, dwh, dwl, INNER * INNER / 4);
    cvt_hilo<<<dim3(D_MODEL * INNER / 4 / 256), blk, 0, stream>>>(out_w, owh, owl, D_MODEL * INNER / 4);

    // 1) in_proj (MFMA split-bf16): xz = hs @ in_w^T
    gemm_mfma<0><<<dim3(2 * INNER / 128, M_TOK / 128), blk, 0, stream>>>(
        hsh, hsl, iwh, iwl, xz, nullptr, nullptr, M_TOK, 2 * INNER, D_MODEL);

    // 2) conv + SiLU -> u (fp32 + hi/lo)
    conv_silu_kernel<<<dim3((M_TOK * (INNER / 4)) / 256), blk, 0, stream>>>(
        xz, conv_w, conv_b, u, uh, ul);

    // 3) dt = softplus(u @ dt_w^T + biases)
    gemm_mfma<1><<<dim3(INNER / 128, M_TOK / 128), blk, 0, stream>>>(
        uh, ul, dwh, dwl, dt, dt_b, dt_bias, M_TOK, INNER, INNER);

    // 4) chunked selective scan; gated output -> yg hi/lo
    scan_pass1<<<dim3(NCH / 16, NCHUNK), blk, 0, stream>>>(
        dt, u, A_log, Bp, hend, Pprod);
    scan_combine<<<dim3((NCH * D_STATE) / 256), blk, 0, stream>>>(
        hend, Pprod, h0all);
    scan_pass2<<<dim3(NCH / 16, NCHUNK), blk, 0, stream>>>(
        dt, u, xz, A_log, Bp, Cp, Dp, h0all, ygh, ygl);

    // 5) out_proj: out = yg @ out_w^T
    gemm_mfma<0><<<dim3(D_MODEL / 128, M_TOK / 128), blk, 0, stream>>>(
        ygh, ygl, owh, owl, out, nullptr, nullptr, M_TOK, D_MODEL, INNER);
}

// Round 4
// 368.170 us; speedup vs baseline: 4.2371x; 1.1483x over previous
//
#include <hip/hip_runtime.h>
#include <cstdint>
#include <cstddef>

#define D_MODEL 768
#define D_STATE 16
#define D_CONV  4
#define INNER   1536
#define BATCH   2
#define SEQLEN  2048
#define M_TOK   (BATCH * SEQLEN)   // 4096
#define NCH     (BATCH * INNER)    // 3072
#define NCHUNK  64
#define CL      (SEQLEN / NCHUNK)  // 32

typedef unsigned short u16;
typedef __attribute__((ext_vector_type(4))) unsigned short us4;
typedef __attribute__((ext_vector_type(8))) short bf8;
typedef __attribute__((ext_vector_type(4))) float f32x4;

__device__ __forceinline__ u16 f2bf(float f) {
    uint32_t x = __float_as_uint(f);
    return (u16)((x + 0x7fffu + ((x >> 16) & 1u)) >> 16);
}
__device__ __forceinline__ float bf2f(u16 h) {
    return __uint_as_float(((uint32_t)h) << 16);
}

// ---------------------------------------------------------------------------
// fp32 -> (hi, lo) bf16 split, vectorized x4
// ---------------------------------------------------------------------------
__global__ __launch_bounds__(256) void cvt_hilo(
    const float* __restrict__ x, u16* __restrict__ hi, u16* __restrict__ lo, int n4)
{
    const int i = blockIdx.x * 256 + threadIdx.x;
    if (i >= n4) return;
    const float4 v = ((const float4*)x)[i];
    us4 h, l;
    h.x = f2bf(v.x); l.x = f2bf(v.x - bf2f(h.x));
    h.y = f2bf(v.y); l.y = f2bf(v.y - bf2f(h.y));
    h.z = f2bf(v.z); l.z = f2bf(v.z - bf2f(h.z));
    h.w = f2bf(v.w); l.w = f2bf(v.w - bf2f(h.w));
    ((us4*)hi)[i] = h;
    ((us4*)lo)[i] = l;
}

// ---------------------------------------------------------------------------
// Split-bf16 MFMA GEMM: C[m,n] = sum_k A[m,k]*B[n,k]  (A,B as hi/lo bf16).
// 128x128 tile, BK=32, 4 waves (64x64 out each), acc += Ah*Bh + Ah*Bl + Al*Bh.
// MODE 0: plain store. MODE 1: softplus(v + bias1[n] + bias2[n]).
// ---------------------------------------------------------------------------
template <int MODE>
__global__ __launch_bounds__(256) void gemm_mfma(
    const u16* __restrict__ Ah_g, const u16* __restrict__ Al_g,
    const u16* __restrict__ Bh_g, const u16* __restrict__ Bl_g,
    float* __restrict__ C, const float* __restrict__ bias1,
    const float* __restrict__ bias2, int M, int N, int K)
{
    __shared__ u16 sAh[128 * 32], sAl[128 * 32], sBh[128 * 32], sBl[128 * 32];
    const int tid = threadIdx.x;
    const int w = tid >> 6;
    const int lane = tid & 63;
    const int bm = blockIdx.y * 128;
    const int bn = blockIdx.x * 128;
    const int wm = (w >> 1) * 64;
    const int wn = (w & 1) * 64;

    const int st_row = w * 16 + (lane >> 2);
    const int st_col = (lane & 3) * 8;
    const u16* a_h = Ah_g + (size_t)(bm + st_row) * K + st_col;
    const u16* a_l = Al_g + (size_t)(bm + st_row) * K + st_col;
    const u16* b_h = Bh_g + (size_t)(bn + st_row) * K + st_col;
    const u16* b_l = Bl_g + (size_t)(bn + st_row) * K + st_col;
    const size_t rowskip = (size_t)64 * K;

    f32x4 acc[4][4] = {};

    const int fr = lane & 15;
    const int fk = (lane >> 4) * 8;

    for (int k0 = 0; k0 < K; k0 += 32) {
        __syncthreads();
#define STAGE(gp, lds)                                                              \
        __builtin_amdgcn_global_load_lds(                                           \
            (const __attribute__((address_space(1))) void*)(gp + k0),               \
            (__attribute__((address_space(3))) void*)((char*)(lds) + w * 1024),     \
            16, 0, 0);                                                              \
        __builtin_amdgcn_global_load_lds(                                           \
            (const __attribute__((address_space(1))) void*)(gp + k0 + rowskip),     \
            (__attribute__((address_space(3))) void*)((char*)(lds) + 4096 + w * 1024), \
            16, 0, 0);
        STAGE(a_h, sAh) STAGE(a_l, sAl) STAGE(b_h, sBh) STAGE(b_l, sBl)
#undef STAGE
        asm volatile("s_waitcnt vmcnt(0)" ::: "memory");
        __syncthreads();

        bf8 ah[4], al[4], bh[4], bl[4];
#pragma unroll
        for (int i = 0; i < 4; ++i) {
            ah[i] = *(const bf8*)&sAh[(wm + i * 16 + fr) * 32 + fk];
            al[i] = *(const bf8*)&sAl[(wm + i * 16 + fr) * 32 + fk];
            bh[i] = *(const bf8*)&sBh[(wn + i * 16 + fr) * 32 + fk];
            bl[i] = *(const bf8*)&sBl[(wn + i * 16 + fr) * 32 + fk];
        }
#pragma unroll
        for (int i = 0; i < 4; ++i)
#pragma unroll
            for (int j = 0; j < 4; ++j) {
                acc[i][j] = __builtin_amdgcn_mfma_f32_16x16x32_bf16(ah[i], bh[j], acc[i][j], 0, 0, 0);
                acc[i][j] = __builtin_amdgcn_mfma_f32_16x16x32_bf16(ah[i], bl[j], acc[i][j], 0, 0, 0);
                acc[i][j] = __builtin_amdgcn_mfma_f32_16x16x32_bf16(al[i], bh[j], acc[i][j], 0, 0, 0);
            }
    }

    const int r0 = (lane >> 4) * 4;
#pragma unroll
    for (int i = 0; i < 4; ++i) {
        const int row0 = bm + wm + i * 16 + r0;
#pragma unroll
        for (int j = 0; j < 4; ++j) {
            const int col = bn + wn + j * 16 + fr;
            float add = 0.f;
            if constexpr (MODE == 1) add = bias1[col] + bias2[col];
#pragma unroll
            for (int r = 0; r < 4; ++r) {
                float v = acc[i][j][r];
                if constexpr (MODE == 1) {
                    const float xx = v + add;
                    v = (xx > 20.f) ? xx : log1pf(expf(xx));
                }
                C[(size_t)(row0 + r) * N + col] = v;
            }
        }
    }
}

// ---------------------------------------------------------------------------
// Depthwise causal conv (width 4) + bias + SiLU -> u hi/lo bf16 only
// ---------------------------------------------------------------------------
__global__ __launch_bounds__(256) void conv_silu_kernel(
    const float* __restrict__ xz, const float* __restrict__ cw,
    const float* __restrict__ cb, u16* __restrict__ uh, u16* __restrict__ ul)
{
    const int idx = blockIdx.x * 256 + threadIdx.x;
    const int c4 = (idx % (INNER / 4)) * 4;
    const int m  = idx / (INNER / 4);
    if (m >= M_TOK) return;
    const int b = m >> 11;
    const int l = m & (SEQLEN - 1);

    float wt[4][4];
#pragma unroll
    for (int i = 0; i < 4; ++i) {
        const float4 wv = *(const float4*)&cw[(c4 + i) * 4];
        wt[i][0] = wv.x; wt[i][1] = wv.y; wt[i][2] = wv.z; wt[i][3] = wv.w;
    }
    const float4 bias = *(const float4*)&cb[c4];
    float a[4] = {bias.x, bias.y, bias.z, bias.w};

#pragma unroll
    for (int j = 0; j < 4; ++j) {
        const int ll = l - 3 + j;
        if (ll >= 0) {
            const float4 x = *(const float4*)&xz[(size_t)(b * SEQLEN + ll) * (2 * INNER) + c4];
            a[0] = fmaf(x.x, wt[0][j], a[0]);
            a[1] = fmaf(x.y, wt[1][j], a[1]);
            a[2] = fmaf(x.z, wt[2][j], a[2]);
            a[3] = fmaf(x.w, wt[3][j], a[3]);
        }
    }
    float o[4];
#pragma unroll
    for (int i = 0; i < 4; ++i) o[i] = a[i] / (1.f + __expf(-a[i]));

    us4 h, lo;
    h.x = f2bf(o[0]); lo.x = f2bf(o[0] - bf2f(h.x));
    h.y = f2bf(o[1]); lo.y = f2bf(o[1] - bf2f(h.y));
    h.z = f2bf(o[2]); lo.z = f2bf(o[2] - bf2f(h.z));
    h.w = f2bf(o[3]); lo.w = f2bf(o[3] - bf2f(h.w));
    const size_t vi = ((size_t)m * INNER + c4) / 4;
    ((us4*)uh)[vi] = h;
    ((us4*)ul)[vi] = lo;
}

// ---------------------------------------------------------------------------
// Scan pass 1: one LANE per channel, 16 states in registers, no shuffles.
// Chunk-local scan with h0=0; emits end-state h[16] and S = sum(dt).
// (prod of dA over the chunk == exp2(A2 * S) — computed in combine.)
// Layout: hend[c][n][NCH], Sdt[c][NCH].  Grid (NCH/256, NCHUNK).
// ---------------------------------------------------------------------------
__global__ __launch_bounds__(256) void scan_pass1(
    const float* __restrict__ dt, const u16* __restrict__ uh,
    const u16* __restrict__ ul, const float* __restrict__ A_log,
    const float* __restrict__ Bp, float* __restrict__ hend,
    float* __restrict__ Sdt)
{
    const int ch = blockIdx.x * 256 + threadIdx.x;   // 0..NCH-1
    const int c = blockIdx.y;
    const int b = (ch >= INNER) ? 1 : 0;
    const int d = ch - b * INNER;

    float A2[D_STATE], Bn[D_STATE];
#pragma unroll
    for (int n = 0; n < D_STATE; n += 4) {
        const float4 av = *(const float4*)&A_log[d * D_STATE + n];
        const float4 bv = *(const float4*)&Bp[d * D_STATE + n];
        A2[n+0] = -expf(av.x) * 1.44269504f; Bn[n+0] = bv.x;
        A2[n+1] = -expf(av.y) * 1.44269504f; Bn[n+1] = bv.y;
        A2[n+2] = -expf(av.z) * 1.44269504f; Bn[n+2] = bv.z;
        A2[n+3] = -expf(av.w) * 1.44269504f; Bn[n+3] = bv.w;
    }

    const size_t base = (size_t)(b * SEQLEN + c * CL) * INNER + d;
    const float* dtp = dt + base;
    const u16* uhp = uh + base;
    const u16* ulp = ul + base;

    float h[D_STATE] = {};
    float S = 0.f;

    float dtv = dtp[0];
    float uv = bf2f(uhp[0]) + bf2f(ulp[0]);

    for (int l = 0; l < CL; ++l) {
        float dtn = 0.f, un = 0.f;
        if (l + 1 < CL) {
            dtn = dtp[(size_t)(l + 1) * INNER];
            un = bf2f(uhp[(size_t)(l + 1) * INNER]) + bf2f(ulp[(size_t)(l + 1) * INNER]);
        }
        const float dtu = dtv * uv;
        S += dtv;
#pragma unroll
        for (int n = 0; n < D_STATE; ++n) {
            const float dA = exp2f(dtv * A2[n]);
            h[n] = fmaf(dA, h[n], dtu * Bn[n]);
        }
        dtv = dtn; uv = un;
    }

#pragma unroll
    for (int n = 0; n < D_STATE; ++n)
        hend[((size_t)c * D_STATE + n) * NCH + ch] = h[n];
    Sdt[(size_t)c * NCH + ch] = S;
}

// ---------------------------------------------------------------------------
// Combine: per (n, ch), walk the chunks; P_c = exp2(A2 * Sdt_c).
// ---------------------------------------------------------------------------
__global__ __launch_bounds__(256) void scan_combine(
    const float* __restrict__ hend, const float* __restrict__ Sdt,
    const float* __restrict__ A_log, float* __restrict__ h0all)
{
    const int idx = blockIdx.x * 256 + threadIdx.x;   // over D_STATE*NCH, n-major
    const int n = idx / NCH;
    const int ch = idx - n * NCH;
    const int b = (ch >= INNER) ? 1 : 0;
    const int d = ch - b * INNER;
    const float A2 = -expf(A_log[d * D_STATE + n]) * 1.44269504f;

    float h0 = 0.f;
    for (int c = 0; c < NCHUNK; ++c) {
        const size_t o = ((size_t)c * D_STATE + n) * NCH + ch;
        h0all[o] = h0;
        const float P = exp2f(A2 * Sdt[(size_t)c * NCH + ch]);
        h0 = fmaf(P, h0, hend[o]);
    }
}

// ---------------------------------------------------------------------------
// Scan pass 2: lane per channel, states in registers; y=(h.C + D*u)*silu(z)
// -> yg hi/lo bf16.
// ---------------------------------------------------------------------------
__global__ __launch_bounds__(256) void scan_pass2(
    const float* __restrict__ dt, const u16* __restrict__ uh,
    const u16* __restrict__ ul, const float* __restrict__ xz,
    const float* __restrict__ A_log, const float* __restrict__ Bp,
    const float* __restrict__ Cp, const float* __restrict__ Dp,
    const float* __restrict__ h0all, u16* __restrict__ ygh,
    u16* __restrict__ ygl)
{
    const int ch = blockIdx.x * 256 + threadIdx.x;
    const int c = blockIdx.y;
    const int b = (ch >= INNER) ? 1 : 0;
    const int d = ch - b * INNER;

    float A2[D_STATE], Bn[D_STATE], Cn[D_STATE];
#pragma unroll
    for (int n = 0; n < D_STATE; n += 4) {
        const float4 av = *(const float4*)&A_log[d * D_STATE + n];
        const float4 bv = *(const float4*)&Bp[d * D_STATE + n];
        const float4 cv = *(const float4*)&Cp[d * D_STATE + n];
        A2[n+0] = -expf(av.x) * 1.44269504f; Bn[n+0] = bv.x; Cn[n+0] = cv.x;
        A2[n+1] = -expf(av.y) * 1.44269504f; Bn[n+1] = bv.y; Cn[n+1] = cv.y;
        A2[n+2] = -expf(av.z) * 1.44269504f; Bn[n+2] = bv.z; Cn[n+2] = cv.z;
        A2[n+3] = -expf(av.w) * 1.44269504f; Bn[n+3] = bv.w; Cn[n+3] = cv.w;
    }
    const float Dd = Dp[d];

    float h[D_STATE];
#pragma unroll
    for (int n = 0; n < D_STATE; ++n)
        h[n] = h0all[((size_t)c * D_STATE + n) * NCH + ch];

    const size_t base = (size_t)(b * SEQLEN + c * CL) * INNER + d;
    const float* dtp = dt + base;
    const u16* uhp = uh + base;
    const u16* ulp = ul + base;
    const float* zp = xz + (size_t)(b * SEQLEN + c * CL) * (2 * INNER) + INNER + d;
    u16* yhp = ygh + base;
    u16* ylp = ygl + base;

    float dtv = dtp[0];
    float uv = bf2f(uhp[0]) + bf2f(ulp[0]);
    float zv = zp[0];

    for (int l = 0; l < CL; ++l) {
        float dtn = 0.f, un = 0.f, zn = 0.f;
        if (l + 1 < CL) {
            dtn = dtp[(size_t)(l + 1) * INNER];
            un = bf2f(uhp[(size_t)(l + 1) * INNER]) + bf2f(ulp[(size_t)(l + 1) * INNER]);
            zn = zp[(size_t)(l + 1) * (2 * INNER)];
        }
        const float dtu = dtv * uv;
        float y = 0.f;
#pragma unroll
        for (int n = 0; n < D_STATE; ++n) {
            const float dA = exp2f(dtv * A2[n]);
            h[n] = fmaf(dA, h[n], dtu * Bn[n]);
            y = fmaf(h[n], Cn[n], y);
        }
        const float sig = 1.f / (1.f + __expf(-zv));
        const float val = (y + Dd * uv) * (zv * sig);
        const u16 hv = f2bf(val);
        yhp[(size_t)l * INNER] = hv;
        ylp[(size_t)l * INNER] = f2bf(val - bf2f(hv));
        dtv = dtn; uv = un; zv = zn;
    }
}

// ---------------------------------------------------------------------------
extern "C" void kernel_launch(void* const* d_in, const int* in_sizes, int n_in,
                              void* d_out, int out_size, void* d_ws, size_t ws_size,
                              hipStream_t stream)
{
    const float* hs      = (const float*)d_in[0];
    const float* in_w    = (const float*)d_in[1];
    const float* out_w   = (const float*)d_in[2];
    const float* dt_w    = (const float*)d_in[3];
    const float* dt_b    = (const float*)d_in[4];
    const float* conv_w  = (const float*)d_in[5];
    const float* conv_b  = (const float*)d_in[6];
    const float* A_log   = (const float*)d_in[7];
    const float* Bp      = (const float*)d_in[8];
    const float* Cp      = (const float*)d_in[9];
    const float* Dp      = (const float*)d_in[10];
    const float* dt_bias = (const float*)d_in[11];
    float* out = (float*)d_out;

    float* xz    = (float*)d_ws;                                   // [4096,3072] f32
    float* dtf   = xz + (size_t)M_TOK * 2 * INNER;                 // [4096,1536] f32
    float* hend  = dtf + (size_t)M_TOK * INNER;                    // [64,16,3072]
    float* Sdt   = hend + (size_t)NCHUNK * D_STATE * NCH;          // [64,3072]
    float* h0all = Sdt + (size_t)NCHUNK * NCH;                     // [64,16,3072]
    u16* uh  = (u16*)(h0all + (size_t)NCHUNK * D_STATE * NCH);
    u16* ul  = uh  + (size_t)M_TOK * INNER;
    u16* hsh = ul  + (size_t)M_TOK * INNER;
    u16* hsl = hsh + (size_t)M_TOK * D_MODEL;
    u16* ygh = hsl + (size_t)M_TOK * D_MODEL;
    u16* ygl = ygh + (size_t)M_TOK * INNER;
    u16* iwh = ygl + (size_t)M_TOK * INNER;
    u16* iwl = iwh + (size_t)2 * INNER * D_MODEL;
    u16* dwh = iwl + (size_t)2 * INNER * D_MODEL;
    u16* dwl = dwh + (size_t)INNER * INNER;
    u16* owh = dwl + (size_t)INNER * INNER;
    u16* owl = owh + (size_t)D_MODEL * INNER;

    const dim3 blk(256);

    cvt_hilo<<<dim3(M_TOK * D_MODEL / 4 / 256), blk, 0, stream>>>(hs, hsh, hsl, M_TOK * D_MODEL / 4);
    cvt_hilo<<<dim3(2 * INNER * D_MODEL / 4 / 256), blk, 0, stream>>>(in_w, iwh, iwl, 2 * INNER * D_MODEL / 4);
    cvt_hilo<<<dim3(INNER * INNER / 4 / 256), blk, 0, stream>>>(dt_w, dwh, dwl, INNER * INNER / 4);
    cvt_hilo<<<dim3(D_MODEL * INNER / 4 / 256), blk, 0, stream>>>(out_w, owh, owl, D_MODEL * INNER / 4);

    // 1) in_proj: xz = hs @ in_w^T
    gemm_mfma<0><<<dim3(2 * INNER / 128, M_TOK / 128), blk, 0, stream>>>(
        hsh, hsl, iwh, iwl, xz, nullptr, nullptr, M_TOK, 2 * INNER, D_MODEL);

    // 2) conv + SiLU -> u hi/lo
    conv_silu_kernel<<<dim3((M_TOK * (INNER / 4)) / 256), blk, 0, stream>>>(
        xz, conv_w, conv_b, uh, ul);

    // 3) dt = softplus(u @ dt_w^T + biases)
    gemm_mfma<1><<<dim3(INNER / 128, M_TOK / 128), blk, 0, stream>>>(
        uh, ul, dwh, dwl, dtf, dt_b, dt_bias, M_TOK, INNER, INNER);

    // 4) chunked selective scan (lane-per-channel, register states)
    scan_pass1<<<dim3(NCH / 256, NCHUNK), blk, 0, stream>>>(
        dtf, uh, ul, A_log, Bp, hend, Sdt);
    scan_combine<<<dim3((D_STATE * NCH) / 256), blk, 0, stream>>>(
        hend, Sdt, A_log, h0all);
    scan_pass2<<<dim3(NCH / 256, NCHUNK), blk, 0, stream>>>(
        dtf, uh, ul, xz, A_log, Bp, Cp, Dp, h0all, ygh, ygl);

    // 5) out_proj: out = yg @ out_w^T
    gemm_mfma<0><<<dim3(D_MODEL / 128, M_TOK / 128), blk, 0, stream>>>(
        ygh, ygl, owh, owl, out, nullptr, nullptr, M_TOK, D_MODEL, INNER);
}

// Round 5
// 340.249 us; speedup vs baseline: 4.5848x; 1.0821x over previous
//
#include <hip/hip_runtime.h>
#include <cstdint>
#include <cstddef>

#define D_MODEL 768
#define D_STATE 16
#define D_CONV  4
#define INNER   1536
#define BATCH   2
#define SEQLEN  2048
#define M_TOK   (BATCH * SEQLEN)   // 4096
#define NCH     (BATCH * INNER)    // 3072
#define NCHUNK  64
#define CL      (SEQLEN / NCHUNK)  // 32

typedef unsigned short u16;
typedef __attribute__((ext_vector_type(4))) unsigned short us4;
typedef __attribute__((ext_vector_type(8))) short bf8;
typedef __attribute__((ext_vector_type(4))) float f32x4;

__device__ __forceinline__ u16 f2bf(float f) {
    uint32_t x = __float_as_uint(f);
    return (u16)((x + 0x7fffu + ((x >> 16) & 1u)) >> 16);
}
__device__ __forceinline__ float bf2f(u16 h) {
    return __uint_as_float(((uint32_t)h) << 16);
}

// ---------------------------------------------------------------------------
// fp32 -> (hi, lo) bf16 split, vectorized x4
// ---------------------------------------------------------------------------
__global__ __launch_bounds__(256) void cvt_hilo(
    const float* __restrict__ x, u16* __restrict__ hi, u16* __restrict__ lo, int n4)
{
    const int i = blockIdx.x * 256 + threadIdx.x;
    if (i >= n4) return;
    const float4 v = ((const float4*)x)[i];
    us4 h, l;
    h.x = f2bf(v.x); l.x = f2bf(v.x - bf2f(h.x));
    h.y = f2bf(v.y); l.y = f2bf(v.y - bf2f(h.y));
    h.z = f2bf(v.z); l.z = f2bf(v.z - bf2f(h.z));
    h.w = f2bf(v.w); l.w = f2bf(v.w - bf2f(h.w));
    ((us4*)hi)[i] = h;
    ((us4*)lo)[i] = l;
}

// ---------------------------------------------------------------------------
// Split-bf16 MFMA GEMM: C[m,n] = sum_k A[m,k]*B[n,k]  (A,B as hi/lo bf16).
// Tile BM x 128 (BM = FRM*32), BK=32, 4 waves.
// LDS row = 128B: granules 0..3 = hi k-tile, 4..7 = lo k-tile, XOR-swizzled
// by (row&7). Stage = global_load_lds with pre-swizzled global source
// (linear LDS dest); read applies the same XOR -> conflict-free ds_read_b128.
// Double-buffered: STAGE(t+1) issued first, s_waitcnt vmcnt(N) keeps them in
// flight across the raw s_barriers (never a full drain in the main loop).
// acc += Ah*Bh + Ah*Bl + Al*Bh.  MODE 1: softplus(v + bias1[n] + bias2[n]).
// ---------------------------------------------------------------------------
template <int MODE, int FRM>
__global__ __launch_bounds__(256) void gemm_mfma(
    const u16* __restrict__ Ah_g, const u16* __restrict__ Al_g,
    const u16* __restrict__ Bh_g, const u16* __restrict__ Bl_g,
    float* __restrict__ C, const float* __restrict__ bias1,
    const float* __restrict__ bias2, int M, int N, int K)
{
    constexpr int BM = FRM * 32;
    constexpr int SBUF = (BM + 128) * 128;           // bytes per stage buffer
    __shared__ __align__(16) char smem[2 * SBUF];

    const int tid = threadIdx.x;
    const int w = tid >> 6;
    const int lane = tid & 63;

    // XCD-aware bijective block swizzle (grid counts are multiples of 8)
    const int gx = gridDim.x;
    const int nwg = gx * gridDim.y;
    int f = blockIdx.y * gx + blockIdx.x;
    f = (f & 7) * (nwg >> 3) + (f >> 3);
    const int bm = (f / gx) * BM;
    const int bn = (f % gx) * 128;

    const int wm = (w >> 1) * (FRM * 16);
    const int wn = (w & 1) * 64;

    // --- staging constants (src granule = g ^ (row&7); row&7 == lane>>3) ---
    const int g8 = lane & 7;
    const int r8 = lane >> 3;
    const int src = g8 ^ r8;
    const int scol = (src & 3) * 8;                  // element col in k-tile
    const bool use_lo = (src & 4) != 0;

    const u16* pA[FRM];
    const u16* pB[4];
#pragma unroll
    for (int c = 0; c < FRM; ++c) {
        const int row = w * (FRM * 8) + c * 8 + r8;
        pA[c] = (use_lo ? Al_g : Ah_g) + (size_t)(bm + row) * K + scol;
    }
#pragma unroll
    for (int c = 0; c < 4; ++c) {
        const int row = w * 32 + c * 8 + r8;
        pB[c] = (use_lo ? Bl_g : Bh_g) + (size_t)(bn + row) * K + scol;
    }

    f32x4 acc[FRM][4] = {};
    const int fr = lane & 15;
    const int gk = lane >> 4;                        // hi source granule 0..3
    const int ghi = gk ^ (fr & 7);                   // swizzled LDS granule

    const int nt = K >> 5;

#define STAGE_ALL(p, kt)                                                            \
    {                                                                               \
        char* sb = smem + (p) * SBUF;                                               \
        _Pragma("unroll")                                                           \
        for (int c = 0; c < FRM; ++c)                                               \
            __builtin_amdgcn_global_load_lds(                                       \
                (const __attribute__((address_space(1))) void*)(pA[c] + (kt)),      \
                (__attribute__((address_space(3))) void*)(sb + (w * FRM + c) * 1024), \
                16, 0, 0);                                                          \
        _Pragma("unroll")                                                           \
        for (int c = 0; c < 4; ++c)                                                 \
            __builtin_amdgcn_global_load_lds(                                       \
                (const __attribute__((address_space(1))) void*)(pB[c] + (kt)),      \
                (__attribute__((address_space(3))) void*)(sb + BM * 128 + (w * 4 + c) * 1024), \
                16, 0, 0);                                                          \
    }

    STAGE_ALL(0, 0)

    int p = 0;
    for (int t = 0; t < nt; ++t) {
        if (t + 1 < nt) {
            STAGE_ALL(p ^ 1, (t + 1) * 32)
            if constexpr (FRM == 4) {
                asm volatile("s_waitcnt vmcnt(8)" ::: "memory");
            } else {
                asm volatile("s_waitcnt vmcnt(6)" ::: "memory");
            }
        } else {
            asm volatile("s_waitcnt vmcnt(0)" ::: "memory");
        }
        __builtin_amdgcn_s_barrier();                // buf[p] fully staged
        __builtin_amdgcn_sched_barrier(0);

        const char* A0 = smem + p * SBUF;
        const char* B0 = A0 + BM * 128;
        bf8 ah[FRM], al[FRM], bh[4], bl[4];
#pragma unroll
        for (int i = 0; i < FRM; ++i) {
            const int row = wm + i * 16 + fr;
            ah[i] = *(const bf8*)(A0 + row * 128 + ghi * 16);
            al[i] = *(const bf8*)(A0 + row * 128 + (ghi ^ 4) * 16);
        }
#pragma unroll
        for (int j = 0; j < 4; ++j) {
            const int row = wn + j * 16 + fr;
            bh[j] = *(const bf8*)(B0 + row * 128 + ghi * 16);
            bl[j] = *(const bf8*)(B0 + row * 128 + (ghi ^ 4) * 16);
        }
#pragma unroll
        for (int i = 0; i < FRM; ++i)
#pragma unroll
            for (int j = 0; j < 4; ++j) {
                acc[i][j] = __builtin_amdgcn_mfma_f32_16x16x32_bf16(ah[i], bh[j], acc[i][j], 0, 0, 0);
                acc[i][j] = __builtin_amdgcn_mfma_f32_16x16x32_bf16(ah[i], bl[j], acc[i][j], 0, 0, 0);
                acc[i][j] = __builtin_amdgcn_mfma_f32_16x16x32_bf16(al[i], bh[j], acc[i][j], 0, 0, 0);
            }

        __builtin_amdgcn_sched_barrier(0);
        __builtin_amdgcn_s_barrier();                // all reads of buf[p] done
        p ^= 1;
    }
#undef STAGE_ALL

    const int r0 = (lane >> 4) * 4;
#pragma unroll
    for (int i = 0; i < FRM; ++i) {
        const int row0 = bm + wm + i * 16 + r0;
#pragma unroll
        for (int j = 0; j < 4; ++j) {
            const int col = bn + wn + j * 16 + fr;
            float add = 0.f;
            if constexpr (MODE == 1) add = bias1[col] + bias2[col];
#pragma unroll
            for (int r = 0; r < 4; ++r) {
                float v = acc[i][j][r];
                if constexpr (MODE == 1) {
                    const float xx = v + add;
                    v = (xx > 20.f) ? xx : log1pf(expf(xx));
                }
                C[(size_t)(row0 + r) * N + col] = v;
            }
        }
    }
}

// ---------------------------------------------------------------------------
// Depthwise causal conv (width 4) + bias + SiLU -> u hi/lo bf16
// ---------------------------------------------------------------------------
__global__ __launch_bounds__(256) void conv_silu_kernel(
    const float* __restrict__ xz, const float* __restrict__ cw,
    const float* __restrict__ cb, u16* __restrict__ uh, u16* __restrict__ ul)
{
    const int idx = blockIdx.x * 256 + threadIdx.x;
    const int c4 = (idx % (INNER / 4)) * 4;
    const int m  = idx / (INNER / 4);
    if (m >= M_TOK) return;
    const int b = m >> 11;
    const int l = m & (SEQLEN - 1);

    float wt[4][4];
#pragma unroll
    for (int i = 0; i < 4; ++i) {
        const float4 wv = *(const float4*)&cw[(c4 + i) * 4];
        wt[i][0] = wv.x; wt[i][1] = wv.y; wt[i][2] = wv.z; wt[i][3] = wv.w;
    }
    const float4 bias = *(const float4*)&cb[c4];
    float a[4] = {bias.x, bias.y, bias.z, bias.w};

#pragma unroll
    for (int j = 0; j < 4; ++j) {
        const int ll = l - 3 + j;
        if (ll >= 0) {
            const float4 x = *(const float4*)&xz[(size_t)(b * SEQLEN + ll) * (2 * INNER) + c4];
            a[0] = fmaf(x.x, wt[0][j], a[0]);
            a[1] = fmaf(x.y, wt[1][j], a[1]);
            a[2] = fmaf(x.z, wt[2][j], a[2]);
            a[3] = fmaf(x.w, wt[3][j], a[3]);
        }
    }
    float o[4];
#pragma unroll
    for (int i = 0; i < 4; ++i) o[i] = a[i] / (1.f + __expf(-a[i]));

    us4 h, lo;
    h.x = f2bf(o[0]); lo.x = f2bf(o[0] - bf2f(h.x));
    h.y = f2bf(o[1]); lo.y = f2bf(o[1] - bf2f(h.y));
    h.z = f2bf(o[2]); lo.z = f2bf(o[2] - bf2f(h.z));
    h.w = f2bf(o[3]); lo.w = f2bf(o[3] - bf2f(h.w));
    const size_t vi = ((size_t)m * INNER + c4) / 4;
    ((us4*)uh)[vi] = h;
    ((us4*)ul)[vi] = lo;
}

// ---------------------------------------------------------------------------
// Scan pass 1: one lane per channel, 16 states in registers, no shuffles.
// ---------------------------------------------------------------------------
__global__ __launch_bounds__(256) void scan_pass1(
    const float* __restrict__ dt, const u16* __restrict__ uh,
    const u16* __restrict__ ul, const float* __restrict__ A_log,
    const float* __restrict__ Bp, float* __restrict__ hend,
    float* __restrict__ Sdt)
{
    const int ch = blockIdx.x * 256 + threadIdx.x;
    const int c = blockIdx.y;
    const int b = (ch >= INNER) ? 1 : 0;
    const int d = ch - b * INNER;

    float A2[D_STATE], Bn[D_STATE];
#pragma unroll
    for (int n = 0; n < D_STATE; n += 4) {
        const float4 av = *(const float4*)&A_log[d * D_STATE + n];
        const float4 bv = *(const float4*)&Bp[d * D_STATE + n];
        A2[n+0] = -expf(av.x) * 1.44269504f; Bn[n+0] = bv.x;
        A2[n+1] = -expf(av.y) * 1.44269504f; Bn[n+1] = bv.y;
        A2[n+2] = -expf(av.z) * 1.44269504f; Bn[n+2] = bv.z;
        A2[n+3] = -expf(av.w) * 1.44269504f; Bn[n+3] = bv.w;
    }

    const size_t base = (size_t)(b * SEQLEN + c * CL) * INNER + d;
    const float* dtp = dt + base;
    const u16* uhp = uh + base;
    const u16* ulp = ul + base;

    float h[D_STATE] = {};
    float S = 0.f;

    float dtv = dtp[0];
    float uv = bf2f(uhp[0]) + bf2f(ulp[0]);

    for (int l = 0; l < CL; ++l) {
        float dtn = 0.f, un = 0.f;
        if (l + 1 < CL) {
            dtn = dtp[(size_t)(l + 1) * INNER];
            un = bf2f(uhp[(size_t)(l + 1) * INNER]) + bf2f(ulp[(size_t)(l + 1) * INNER]);
        }
        const float dtu = dtv * uv;
        S += dtv;
#pragma unroll
        for (int n = 0; n < D_STATE; ++n) {
            const float dA = exp2f(dtv * A2[n]);
            h[n] = fmaf(dA, h[n], dtu * Bn[n]);
        }
        dtv = dtn; uv = un;
    }

#pragma unroll
    for (int n = 0; n < D_STATE; ++n)
        hend[((size_t)c * D_STATE + n) * NCH + ch] = h[n];
    Sdt[(size_t)c * NCH + ch] = S;
}

// ---------------------------------------------------------------------------
// Combine: per (n, ch), walk chunks; P_c = exp2(A2 * Sdt_c).
// ---------------------------------------------------------------------------
__global__ __launch_bounds__(256) void scan_combine(
    const float* __restrict__ hend, const float* __restrict__ Sdt,
    const float* __restrict__ A_log, float* __restrict__ h0all)
{
    const int idx = blockIdx.x * 256 + threadIdx.x;
    const int n = idx / NCH;
    const int ch = idx - n * NCH;
    const int b = (ch >= INNER) ? 1 : 0;
    const int d = ch - b * INNER;
    const float A2 = -expf(A_log[d * D_STATE + n]) * 1.44269504f;

    float h0 = 0.f;
    for (int c = 0; c < NCHUNK; ++c) {
        const size_t o = ((size_t)c * D_STATE + n) * NCH + ch;
        h0all[o] = h0;
        const float P = exp2f(A2 * Sdt[(size_t)c * NCH + ch]);
        h0 = fmaf(P, h0, hend[o]);
    }
}

// ---------------------------------------------------------------------------
// Scan pass 2: lane per channel; y=(h.C + D*u)*silu(z) -> yg hi/lo bf16.
// ---------------------------------------------------------------------------
__global__ __launch_bounds__(256) void scan_pass2(
    const float* __restrict__ dt, const u16* __restrict__ uh,
    const u16* __restrict__ ul, const float* __restrict__ xz,
    const float* __restrict__ A_log, const float* __restrict__ Bp,
    const float* __restrict__ Cp, const float* __restrict__ Dp,
    const float* __restrict__ h0all, u16* __restrict__ ygh,
    u16* __restrict__ ygl)
{
    const int ch = blockIdx.x * 256 + threadIdx.x;
    const int c = blockIdx.y;
    const int b = (ch >= INNER) ? 1 : 0;
    const int d = ch - b * INNER;

    float A2[D_STATE], Bn[D_STATE], Cn[D_STATE];
#pragma unroll
    for (int n = 0; n < D_STATE; n += 4) {
        const float4 av = *(const float4*)&A_log[d * D_STATE + n];
        const float4 bv = *(const float4*)&Bp[d * D_STATE + n];
        const float4 cv = *(const float4*)&Cp[d * D_STATE + n];
        A2[n+0] = -expf(av.x) * 1.44269504f; Bn[n+0] = bv.x; Cn[n+0] = cv.x;
        A2[n+1] = -expf(av.y) * 1.44269504f; Bn[n+1] = bv.y; Cn[n+1] = cv.y;
        A2[n+2] = -expf(av.z) * 1.44269504f; Bn[n+2] = bv.z; Cn[n+2] = cv.z;
        A2[n+3] = -expf(av.w) * 1.44269504f; Bn[n+3] = bv.w; Cn[n+3] = cv.w;
    }
    const float Dd = Dp[d];

    float h[D_STATE];
#pragma unroll
    for (int n = 0; n < D_STATE; ++n)
        h[n] = h0all[((size_t)c * D_STATE + n) * NCH + ch];

    const size_t base = (size_t)(b * SEQLEN + c * CL) * INNER + d;
    const float* dtp = dt + base;
    const u16* uhp = uh + base;
    const u16* ulp = ul + base;
    const float* zp = xz + (size_t)(b * SEQLEN + c * CL) * (2 * INNER) + INNER + d;
    u16* yhp = ygh + base;
    u16* ylp = ygl + base;

    float dtv = dtp[0];
    float uv = bf2f(uhp[0]) + bf2f(ulp[0]);
    float zv = zp[0];

    for (int l = 0; l < CL; ++l) {
        float dtn = 0.f, un = 0.f, zn = 0.f;
        if (l + 1 < CL) {
            dtn = dtp[(size_t)(l + 1) * INNER];
            un = bf2f(uhp[(size_t)(l + 1) * INNER]) + bf2f(ulp[(size_t)(l + 1) * INNER]);
            zn = zp[(size_t)(l + 1) * (2 * INNER)];
        }
        const float dtu = dtv * uv;
        float y = 0.f;
#pragma unroll
        for (int n = 0; n < D_STATE; ++n) {
            const float dA = exp2f(dtv * A2[n]);
            h[n] = fmaf(dA, h[n], dtu * Bn[n]);
            y = fmaf(h[n], Cn[n], y);
        }
        const float sig = 1.f / (1.f + __expf(-zv));
        const float val = (y + Dd * uv) * (zv * sig);
        const u16 hv = f2bf(val);
        yhp[(size_t)l * INNER] = hv;
        ylp[(size_t)l * INNER] = f2bf(val - bf2f(hv));
        dtv = dtn; uv = un; zv = zn;
    }
}

// ---------------------------------------------------------------------------
extern "C" void kernel_launch(void* const* d_in, const int* in_sizes, int n_in,
                              void* d_out, int out_size, void* d_ws, size_t ws_size,
                              hipStream_t stream)
{
    const float* hs      = (const float*)d_in[0];
    const float* in_w    = (const float*)d_in[1];
    const float* out_w   = (const float*)d_in[2];
    const float* dt_w    = (const float*)d_in[3];
    const float* dt_b    = (const float*)d_in[4];
    const float* conv_w  = (const float*)d_in[5];
    const float* conv_b  = (const float*)d_in[6];
    const float* A_log   = (const float*)d_in[7];
    const float* Bp      = (const float*)d_in[8];
    const float* Cp      = (const float*)d_in[9];
    const float* Dp      = (const float*)d_in[10];
    const float* dt_bias = (const float*)d_in[11];
    float* out = (float*)d_out;

    float* xz    = (float*)d_ws;                                   // [4096,3072] f32
    float* dtf   = xz + (size_t)M_TOK * 2 * INNER;                 // [4096,1536] f32
    float* hend  = dtf + (size_t)M_TOK * INNER;                    // [64,16,3072]
    float* Sdt   = hend + (size_t)NCHUNK * D_STATE * NCH;          // [64,3072]
    float* h0all = Sdt + (size_t)NCHUNK * NCH;                     // [64,16,3072]
    u16* uh  = (u16*)(h0all + (size_t)NCHUNK * D_STATE * NCH);
    u16* ul  = uh  + (size_t)M_TOK * INNER;
    u16* hsh = ul  + (size_t)M_TOK * INNER;
    u16* hsl = hsh + (size_t)M_TOK * D_MODEL;
    u16* ygh = hsl + (size_t)M_TOK * D_MODEL;
    u16* ygl = ygh + (size_t)M_TOK * INNER;
    u16* iwh = ygl + (size_t)M_TOK * INNER;
    u16* iwl = iwh + (size_t)2 * INNER * D_MODEL;
    u16* dwh = iwl + (size_t)2 * INNER * D_MODEL;
    u16* dwl = dwh + (size_t)INNER * INNER;
    u16* owh = dwl + (size_t)INNER * INNER;
    u16* owl = owh + (size_t)D_MODEL * INNER;

    const dim3 blk(256);

    cvt_hilo<<<dim3(M_TOK * D_MODEL / 4 / 256), blk, 0, stream>>>(hs, hsh, hsl, M_TOK * D_MODEL / 4);
    cvt_hilo<<<dim3(2 * INNER * D_MODEL / 4 / 256), blk, 0, stream>>>(in_w, iwh, iwl, 2 * INNER * D_MODEL / 4);
    cvt_hilo<<<dim3(INNER * INNER / 4 / 256), blk, 0, stream>>>(dt_w, dwh, dwl, INNER * INNER / 4);
    cvt_hilo<<<dim3(D_MODEL * INNER / 4 / 256), blk, 0, stream>>>(out_w, owh, owl, D_MODEL * INNER / 4);

    // 1) in_proj: xz = hs @ in_w^T   (grid 24x32 = 768 blocks)
    gemm_mfma<0, 4><<<dim3(2 * INNER / 128, M_TOK / 128), blk, 0, stream>>>(
        hsh, hsl, iwh, iwl, xz, nullptr, nullptr, M_TOK, 2 * INNER, D_MODEL);

    // 2) conv + SiLU -> u hi/lo
    conv_silu_kernel<<<dim3((M_TOK * (INNER / 4)) / 256), blk, 0, stream>>>(
        xz, conv_w, conv_b, uh, ul);

    // 3) dt = softplus(u @ dt_w^T + biases)   (grid 12x32 = 384 blocks)
    gemm_mfma<1, 4><<<dim3(INNER / 128, M_TOK / 128), blk, 0, stream>>>(
        uh, ul, dwh, dwl, dtf, dt_b, dt_bias, M_TOK, INNER, INNER);

    // 4) chunked selective scan
    scan_pass1<<<dim3(NCH / 256, NCHUNK), blk, 0, stream>>>(
        dtf, uh, ul, A_log, Bp, hend, Sdt);
    scan_combine<<<dim3((D_STATE * NCH) / 256), blk, 0, stream>>>(
        hend, Sdt, A_log, h0all);
    scan_pass2<<<dim3(NCH / 256, NCHUNK), blk, 0, stream>>>(
        dtf, uh, ul, xz, A_log, Bp, Cp, Dp, h0all, ygh, ygl);

    // 5) out_proj: out = yg @ out_w^T   (BM=64: grid 6x64 = 384 blocks)
    gemm_mfma<0, 2><<<dim3(D_MODEL / 128, M_TOK / 64), blk, 0, stream>>>(
        ygh, ygl, owh, owl, out, nullptr, nullptr, M_TOK, D_MODEL, INNER);
}